// Round 3
// baseline (582.613 us; speedup 1.0000x reference)
//
#include <hip/hip_runtime.h>
#include <hip/hip_bf16.h>
#include <stdint.h>

namespace {

constexpr int kB = 2;
constexpr int kN = 2048;
constexpr int kC = 1024;
constexpr int kH = 16;
constexpr int kD = 64;
constexpr int kTok = kB * kN;           // 4096
constexpr int k3C  = 3 * kC;            // 3072
constexpr size_t kPS = (size_t)kTok * k3C;  // plane size: 12.58M elems

using bhalf8 = __attribute__((ext_vector_type(8))) __bf16;
using f32x4  = __attribute__((ext_vector_type(4))) float;

__device__ inline unsigned short f2bf(float f) {
  __hip_bfloat16 h = __float2bfloat16(f);
  return *reinterpret_cast<unsigned short*>(&h);
}
__device__ inline float bf2f(unsigned short u) {
  __hip_bfloat16 h;
  *reinterpret_cast<unsigned short*>(&h) = u;
  return __bfloat162float(h);
}
__device__ inline void split2(float v, unsigned short& h, unsigned short& l) {
  const unsigned short hb = f2bf(v);
  h = hb;
  l = f2bf(v - bf2f(hb));
}
__device__ inline float safe_exp(float x) { return __expf(fmaxf(x, -80.0f)); }

// ---- split-precision GEMM: C(MxN) = A(MxK) @ W(NxK)^T + bias ----
// A: fp32 (AFP32) or hi/lo bf16 planes. W: fp32, split on stage. 3-term MFMA.
// Out: fp32 (OUTF32) or hi/lo bf16 planes. 128x128 tile, BK=32, 4 waves 2x2.
template<bool AFP32, bool OUTF32>
__global__ __launch_bounds__(256)
void gemm3(const float* __restrict__ Af,
           const unsigned short* __restrict__ AH,
           const unsigned short* __restrict__ AL, int lda,
           const float* __restrict__ Wf,
           const float* __restrict__ bias,
           float* __restrict__ OutF,
           unsigned short* __restrict__ OutH,
           unsigned short* __restrict__ OutL,
           int Nn, int K)
{
  __shared__ __align__(16) unsigned short AsH[128 * 32], AsL[128 * 32];
  __shared__ __align__(16) unsigned short BsH[128 * 32], BsL[128 * 32];

  const int t    = threadIdx.x;
  const int wave = t >> 6;
  const int lane = t & 63;
  const int quad = lane >> 4;
  const int l16  = lane & 15;
  const int bm = blockIdx.x * 128;
  const int bn = blockIdx.y * 128;
  const int wm = (wave >> 1) * 64;
  const int wn = (wave & 1) * 64;

  f32x4 acc[4][4] = {};

  for (int k0 = 0; k0 < K; k0 += 32) {
    // W (fp32 -> hi/lo): 128x32 floats = 1024 float4 chunks, 4/thread
    #pragma unroll
    for (int r = 0; r < 4; ++r) {
      const int c = r * 256 + t;
      const int row = c >> 3;
      const int col = (c & 7) * 4;
      const float4 w4 = *(const float4*)(&Wf[(size_t)(bn + row) * K + k0 + col]);
      ushort4 hh, ll;
      split2(w4.x, hh.x, ll.x); split2(w4.y, hh.y, ll.y);
      split2(w4.z, hh.z, ll.z); split2(w4.w, hh.w, ll.w);
      *(ushort4*)(&BsH[row * 32 + col]) = hh;
      *(ushort4*)(&BsL[row * 32 + col]) = ll;
    }
    if (AFP32) {
      #pragma unroll
      for (int r = 0; r < 4; ++r) {
        const int c = r * 256 + t;
        const int row = c >> 3;
        const int col = (c & 7) * 4;
        const float4 a4 = *(const float4*)(&Af[(size_t)(bm + row) * lda + k0 + col]);
        ushort4 hh, ll;
        split2(a4.x, hh.x, ll.x); split2(a4.y, hh.y, ll.y);
        split2(a4.z, hh.z, ll.z); split2(a4.w, hh.w, ll.w);
        *(ushort4*)(&AsH[row * 32 + col]) = hh;
        *(ushort4*)(&AsL[row * 32 + col]) = ll;
      }
    } else {
      #pragma unroll
      for (int r = 0; r < 2; ++r) {
        const int c = r * 256 + t;      // 512 chunks of 8 u16
        const int row = c >> 2;
        const int col = (c & 3) * 8;
        *(uint4*)(&AsH[c * 8]) = *(const uint4*)(&AH[(size_t)(bm + row) * lda + k0 + col]);
        *(uint4*)(&AsL[c * 8]) = *(const uint4*)(&AL[(size_t)(bm + row) * lda + k0 + col]);
      }
    }
    __syncthreads();

    bhalf8 afh[4], afl[4], bgh[4], bgl[4];
    #pragma unroll
    for (int i = 0; i < 4; ++i) {
      afh[i] = *(const bhalf8*)(&AsH[(wm + i * 16 + l16) * 32 + quad * 8]);
      afl[i] = *(const bhalf8*)(&AsL[(wm + i * 16 + l16) * 32 + quad * 8]);
      bgh[i] = *(const bhalf8*)(&BsH[(wn + i * 16 + l16) * 32 + quad * 8]);
      bgl[i] = *(const bhalf8*)(&BsL[(wn + i * 16 + l16) * 32 + quad * 8]);
    }
    #pragma unroll
    for (int i = 0; i < 4; ++i)
      #pragma unroll
      for (int j = 0; j < 4; ++j) {
        f32x4 a = acc[i][j];
        a = __builtin_amdgcn_mfma_f32_16x16x32_bf16(afh[i], bgh[j], a, 0, 0, 0);
        a = __builtin_amdgcn_mfma_f32_16x16x32_bf16(afh[i], bgl[j], a, 0, 0, 0);
        a = __builtin_amdgcn_mfma_f32_16x16x32_bf16(afl[i], bgh[j], a, 0, 0, 0);
        acc[i][j] = a;
      }
    __syncthreads();
  }

  // epilogue: C/D layout col=lane&15, row=quad*4+reg
  #pragma unroll
  for (int j = 0; j < 4; ++j) {
    const int n = bn + wn + j * 16 + l16;
    const float bv = bias[n];
    #pragma unroll
    for (int i = 0; i < 4; ++i)
      #pragma unroll
      for (int r = 0; r < 4; ++r) {
        const int m = bm + wm + i * 16 + quad * 4 + r;
        const float v = acc[i][j][r] + bv;
        if (OUTF32) {
          OutF[(size_t)m * Nn + n] = v;
        } else {
          unsigned short hh, ll;
          split2(v, hh, ll);
          OutH[(size_t)m * Nn + n] = hh;
          OutL[(size_t)m * Nn + n] = ll;
        }
      }
  }
}

// ---- RMSNorm over D=64 on q,k slices of the hi/lo qkv planes, in place ----
__global__ __launch_bounds__(256)
void rmsnorm_qk(unsigned short* __restrict__ H, unsigned short* __restrict__ L,
                const float* __restrict__ qn, const float* __restrict__ kn)
{
  const int rid  = blockIdx.x * 4 + (threadIdx.x >> 6);  // 0 .. 2*Tok*H-1
  const int lane = threadIdx.x & 63;
  const int which = rid >> 16;          // 0=q, 1=k (Tok*H = 65536 rows each)
  const int r2    = rid & 65535;
  const int token = r2 >> 4;
  const int h     = r2 & 15;

  const size_t base = (size_t)token * k3C + (size_t)which * kC + h * kD + lane;
  const float x = bf2f(H[base]) + bf2f(L[base]);
  float s = x * x;
  #pragma unroll
  for (int d = 32; d; d >>= 1) s += __shfl_xor(s, d, 64);
  const float rinv = rsqrtf(s * (1.0f / 64.0f) + 1e-6f);
  const float* w = which ? kn : qn;
  float y = w[lane] * (x * rinv);
  if (which == 0) y *= 0.125f;          // q * D^-0.5
  unsigned short hh, ll;
  split2(y, hh, ll);
  H[base] = hh; L[base] = ll;
}

// ---- flash attention on hi/lo planes; output into q-slice in place ----
__global__ __launch_bounds__(256)
void attn_kernel(unsigned short* __restrict__ H, unsigned short* __restrict__ L,
                 const int* __restrict__ mask)
{
  __shared__ __align__(16) unsigned short KtH[64 * 64], KtL[64 * 64]; // [key][d]
  __shared__ __align__(16) unsigned short VtH[64 * 64], VtL[64 * 64]; // [d][key]
  __shared__ __align__(16) float sflag[64];
  __shared__ __align__(16) unsigned short Pt[4][16 * 64];             // [q][key]

  const int t    = threadIdx.x;
  const int wave = t >> 6;
  const int lane = t & 63;
  const int quad = lane >> 4;
  const int l16  = lane & 15;
  const int bh = blockIdx.y;
  const int b  = bh >> 4;
  const int h  = bh & 15;
  const int q0 = blockIdx.x * 64 + wave * 16;

  bhalf8 qfh[2], qfl[2];
  {
    const size_t qrow = (size_t)(b * kN + q0 + l16) * k3C + h * kD;
    qfh[0] = *(const bhalf8*)(&H[qrow + quad * 8]);
    qfh[1] = *(const bhalf8*)(&H[qrow + 32 + quad * 8]);
    qfl[0] = *(const bhalf8*)(&L[qrow + quad * 8]);
    qfl[1] = *(const bhalf8*)(&L[qrow + 32 + quad * 8]);
  }

  f32x4 acc_o[4] = {};
  float m_i[4], l_i[4];
  #pragma unroll
  for (int r = 0; r < 4; ++r) { m_i[r] = -1.0e9f; l_i[r] = 0.0f; }

  for (int kt = 0; kt < kN; kt += 64) {
    #pragma unroll
    for (int rr = 0; rr < 2; ++rr) {
      const int c   = rr * 256 + t;
      const int key = c >> 3;
      const int col = (c & 7) * 8;
      const size_t gb = (size_t)(b * kN + kt + key) * k3C + h * kD + col;
      *(uint4*)(&KtH[c * 8]) = *(const uint4*)(&H[gb + kC]);
      *(uint4*)(&KtL[c * 8]) = *(const uint4*)(&L[gb + kC]);
      uint4 vh = *(const uint4*)(&H[gb + 2 * kC]);
      uint4 vl = *(const uint4*)(&L[gb + 2 * kC]);
      const unsigned short* vhe = (const unsigned short*)&vh;
      const unsigned short* vle = (const unsigned short*)&vl;
      #pragma unroll
      for (int e = 0; e < 8; ++e) {
        VtH[(col + e) * 64 + key] = vhe[e];
        VtL[(col + e) * 64 + key] = vle[e];
      }
    }
    if (t < 64) sflag[t] = (mask[b * kN + kt + t] != 0) ? 1.0f : 0.0f;
    __syncthreads();

    // S = (Qh+Ql)(Kh+Kl)^T ~ QhKh + QhKl + QlKh
    f32x4 sacc[4];
    #pragma unroll
    for (int nt = 0; nt < 4; ++nt) {
      const int kr = (nt * 16 + l16) * 64 + quad * 8;
      bhalf8 bh0 = *(const bhalf8*)(&KtH[kr]);
      bhalf8 bh1 = *(const bhalf8*)(&KtH[kr + 32]);
      bhalf8 bl0 = *(const bhalf8*)(&KtL[kr]);
      bhalf8 bl1 = *(const bhalf8*)(&KtL[kr + 32]);
      f32x4 s = {};
      s = __builtin_amdgcn_mfma_f32_16x16x32_bf16(qfh[0], bh0, s, 0, 0, 0);
      s = __builtin_amdgcn_mfma_f32_16x16x32_bf16(qfh[1], bh1, s, 0, 0, 0);
      s = __builtin_amdgcn_mfma_f32_16x16x32_bf16(qfh[0], bl0, s, 0, 0, 0);
      s = __builtin_amdgcn_mfma_f32_16x16x32_bf16(qfh[1], bl1, s, 0, 0, 0);
      s = __builtin_amdgcn_mfma_f32_16x16x32_bf16(qfl[0], bh0, s, 0, 0, 0);
      s = __builtin_amdgcn_mfma_f32_16x16x32_bf16(qfl[1], bh1, s, 0, 0, 0);
      sacc[nt] = s;
    }

    // mask + online softmax (fp32, matches reference)
    float p[4][4], rowmax[4];
    #pragma unroll
    for (int r = 0; r < 4; ++r) rowmax[r] = -1.0e9f;
    #pragma unroll
    for (int nt = 0; nt < 4; ++nt) {
      const float flag = sflag[nt * 16 + l16];
      #pragma unroll
      for (int r = 0; r < 4; ++r) {
        float s = sacc[nt][r];
        s = (flag != 0.0f) ? s : -1.0e9f;
        p[nt][r] = s;
        rowmax[r] = fmaxf(rowmax[r], s);
      }
    }
    #pragma unroll
    for (int r = 0; r < 4; ++r)
      #pragma unroll
      for (int d = 1; d < 16; d <<= 1)
        rowmax[r] = fmaxf(rowmax[r], __shfl_xor(rowmax[r], d, 64));

    float alpha[4];
    #pragma unroll
    for (int r = 0; r < 4; ++r) {
      const float mn = fmaxf(m_i[r], rowmax[r]);
      alpha[r] = safe_exp(m_i[r] - mn);
      m_i[r] = mn;
      float sum = 0.0f;
      #pragma unroll
      for (int nt = 0; nt < 4; ++nt) {
        const float e = safe_exp(p[nt][r] - mn);
        p[nt][r] = e;
        sum += e;
      }
      #pragma unroll
      for (int d = 1; d < 16; d <<= 1) sum += __shfl_xor(sum, d, 64);
      l_i[r] = l_i[r] * alpha[r] + sum;
      #pragma unroll
      for (int dt = 0; dt < 4; ++dt) acc_o[dt][r] *= alpha[r];
    }

    // P (C-layout) -> LDS (A-layout), bf16 hi
    #pragma unroll
    for (int nt = 0; nt < 4; ++nt)
      #pragma unroll
      for (int r = 0; r < 4; ++r)
        Pt[wave][(quad * 4 + r) * 64 + nt * 16 + l16] = f2bf(p[nt][r]);
    __syncthreads();

    // O += P (Vh + Vl)
    #pragma unroll
    for (int kk = 0; kk < 2; ++kk) {
      bhalf8 pa = *(const bhalf8*)(&Pt[wave][l16 * 64 + kk * 32 + quad * 8]);
      #pragma unroll
      for (int dt = 0; dt < 4; ++dt) {
        const int vr = (dt * 16 + l16) * 64 + kk * 32 + quad * 8;
        bhalf8 vbh = *(const bhalf8*)(&VtH[vr]);
        bhalf8 vbl = *(const bhalf8*)(&VtL[vr]);
        acc_o[dt] = __builtin_amdgcn_mfma_f32_16x16x32_bf16(pa, vbh, acc_o[dt], 0, 0, 0);
        acc_o[dt] = __builtin_amdgcn_mfma_f32_16x16x32_bf16(pa, vbl, acc_o[dt], 0, 0, 0);
      }
    }
    __syncthreads();
  }

  // normalize + store hi/lo into q-slice
  #pragma unroll
  for (int dt = 0; dt < 4; ++dt)
    #pragma unroll
    for (int r = 0; r < 4; ++r) {
      const int qrow = q0 + quad * 4 + r;
      const float inv = 1.0f / fmaxf(l_i[r], 1.0e-30f);
      const size_t off = (size_t)(b * kN + qrow) * k3C + h * kD + dt * 16 + l16;
      unsigned short hh, ll;
      split2(acc_o[dt][r] * inv, hh, ll);
      H[off] = hh; L[off] = ll;
    }
}

} // anonymous namespace

extern "C" void kernel_launch(void* const* d_in, const int* in_sizes, int n_in,
                              void* d_out, int out_size, void* d_ws, size_t ws_size,
                              hipStream_t stream)
{
  const float* x      = (const float*)d_in[0];
  const int*   maskp  = (const int*)d_in[1];
  const float* qkv_w  = (const float*)d_in[2];
  const float* qkv_b  = (const float*)d_in[3];
  const float* proj_w = (const float*)d_in[4];
  const float* proj_b = (const float*)d_in[5];
  const float* qn_w   = (const float*)d_in[6];
  const float* kn_w   = (const float*)d_in[7];
  float* out = (float*)d_out;

  unsigned short* qH = (unsigned short*)d_ws;   // hi plane, 25.2 MB
  unsigned short* qL = qH + kPS;                // lo plane, 25.2 MB

  // 1) qkv = x @ qkv_w^T + qkv_b  (fp32 in, hi/lo planes out)
  gemm3<true, false><<<dim3(kTok / 128, k3C / 128), 256, 0, stream>>>(
      x, nullptr, nullptr, kC, qkv_w, qkv_b, nullptr, qH, qL, k3C, kC);
  // 2) RMSNorm q,k (q also * 1/8)
  rmsnorm_qk<<<(2 * kTok * kH) / 4, 256, 0, stream>>>(qH, qL, qn_w, kn_w);
  // 3) masked flash attention; result into q-slice of planes
  attn_kernel<<<dim3(kN / 64, kB * kH), 256, 0, stream>>>(qH, qL, maskp);
  // 4) out = attn @ proj_w^T + proj_b  (planes in, fp32 out)
  gemm3<false, true><<<dim3(kTok / 128, kC / 128), 256, 0, stream>>>(
      nullptr, qH, qL, k3C, proj_w, proj_b, out, nullptr, nullptr, kC, kC);
}

// Round 4
// 442.655 us; speedup vs baseline: 1.3162x; 1.3162x over previous
//
#include <hip/hip_runtime.h>
#include <hip/hip_bf16.h>
#include <stdint.h>

namespace {

constexpr int kB = 2;
constexpr int kN = 2048;
constexpr int kC = 1024;
constexpr int kH = 16;
constexpr int kD = 64;
constexpr int kTok = kB * kN;               // 4096
constexpr int k3C  = 3 * kC;                // 3072
constexpr size_t kPS = (size_t)kTok * k3C;  // qkv plane elems  12,582,912
constexpr size_t kXE = (size_t)kTok * kC;   // x plane / VT plane elems 4,194,304
constexpr size_t kWQ = (size_t)k3C * kC;    // qkv_w elems 3,145,728
constexpr size_t kWP = (size_t)kC * kC;     // proj_w elems 1,048,576

using bhalf8 = __attribute__((ext_vector_type(8))) __bf16;
using f32x4  = __attribute__((ext_vector_type(4))) float;

__device__ inline unsigned short f2bf(float f) {
  __hip_bfloat16 h = __float2bfloat16(f);
  return *reinterpret_cast<unsigned short*>(&h);
}
__device__ inline float bf2f(unsigned short u) {
  __hip_bfloat16 h;
  *reinterpret_cast<unsigned short*>(&h) = u;
  return __bfloat162float(h);
}
__device__ inline void split2(float v, unsigned short& h, unsigned short& l) {
  const unsigned short hb = f2bf(v);
  h = hb;
  l = f2bf(v - bf2f(hb));
}
__device__ inline float safe_exp(float x) { return __expf(fmaxf(x, -80.0f)); }

// async global->LDS, 16B per lane; LDS dest must be wave-uniform base + lane*16
__device__ inline void glds16(const unsigned short* g, unsigned short* l) {
  __builtin_amdgcn_global_load_lds(
      (const __attribute__((address_space(1))) void*)g,
      (__attribute__((address_space(3))) void*)l, 16, 0, 0);
}

// ---- split fp32 -> bf16 hi/lo planes (vectorized) ----
__global__ __launch_bounds__(256)
void split_planes(const float* __restrict__ src,
                  unsigned short* __restrict__ H,
                  unsigned short* __restrict__ L, int n4)
{
  const int i = blockIdx.x * 256 + threadIdx.x;
  if (i >= n4) return;
  const float4 v = ((const float4*)src)[i];
  ushort4 hh, ll;
  split2(v.x, hh.x, ll.x); split2(v.y, hh.y, ll.y);
  split2(v.z, hh.z, ll.z); split2(v.w, hh.w, ll.w);
  ((ushort4*)H)[i] = hh;
  ((ushort4*)L)[i] = ll;
}

// ---- pre-transpose V slice of qkv planes into VT[bh][d][token] ----
// wave = one (bh, token-octet); lane = d. Reads coalesced (64 consecutive d = 128B).
__global__ __launch_bounds__(256)
void vt_transpose(const unsigned short* __restrict__ H,
                  const unsigned short* __restrict__ L,
                  unsigned short* __restrict__ VTH,
                  unsigned short* __restrict__ VTL)
{
  const int gw   = blockIdx.x * 4 + (threadIdx.x >> 6);  // 0..8191
  const int lane = threadIdx.x & 63;                     // = d
  const int bh   = gw >> 8;                              // 256 octets per bh
  const int oct  = gw & 255;
  const int b = bh >> 4, h = bh & 15;
  const int tok0 = oct * 8;
  union { unsigned short u[8]; uint4 v; } ph, pl;
  #pragma unroll
  for (int e = 0; e < 8; ++e) {
    const size_t g = (size_t)(b * kN + tok0 + e) * k3C + 2 * kC + h * kD + lane;
    ph.u[e] = H[g];
    pl.u[e] = L[g];
  }
  const size_t o = ((size_t)bh * kD + lane) * kN + tok0;
  *(uint4*)(&VTH[o]) = ph.v;
  *(uint4*)(&VTL[o]) = pl.v;
}

// ---- plane GEMM: C(MxN) = (AH+AL)(MxK) @ (WH+WL)(NxK)^T + bias, 3-term MFMA ----
// m97 structure: global_load_lds width-16 staging, 128x128 tile, BK=32, 4 waves 2x2.
template<bool OUTF32>
__global__ __launch_bounds__(256)
void gemm_planes(const unsigned short* __restrict__ AH,
                 const unsigned short* __restrict__ AL, int lda,
                 const unsigned short* __restrict__ WH,
                 const unsigned short* __restrict__ WL,
                 const float* __restrict__ bias,
                 float* __restrict__ OutF,
                 unsigned short* __restrict__ OutH,
                 unsigned short* __restrict__ OutL,
                 int Nn, int K)
{
  // NOTE: unpadded (global_load_lds requires lane-linear LDS layout)
  __shared__ __align__(16) unsigned short AsH[128 * 32], AsL[128 * 32];
  __shared__ __align__(16) unsigned short BsH[128 * 32], BsL[128 * 32];

  const int t    = threadIdx.x;
  const int wave = t >> 6;
  const int lane = t & 63;
  const int quad = lane >> 4;
  const int l16  = lane & 15;
  const int bm = blockIdx.x * 128;
  const int bn = blockIdx.y * 128;
  const int wm = (wave >> 1) * 64;
  const int wn = (wave & 1) * 64;

  f32x4 acc[4][4] = {};

  for (int k0 = 0; k0 < K; k0 += 32) {
    #pragma unroll
    for (int r = 0; r < 2; ++r) {
      const int c   = r * 256 + t;       // 0..511 chunks of 8 u16 (16B)
      const int row = c >> 2;
      const int col = (c & 3) * 8;
      glds16(&AH[(size_t)(bm + row) * lda + k0 + col], &AsH[c * 8]);
      glds16(&AL[(size_t)(bm + row) * lda + k0 + col], &AsL[c * 8]);
      glds16(&WH[(size_t)(bn + row) * K + k0 + col], &BsH[c * 8]);
      glds16(&WL[(size_t)(bn + row) * K + k0 + col], &BsL[c * 8]);
    }
    __syncthreads();   // drains vmcnt (global_load_lds) + lgkm

    bhalf8 afh[4], afl[4], bgh[4], bgl[4];
    #pragma unroll
    for (int i = 0; i < 4; ++i) {
      afh[i] = *(const bhalf8*)(&AsH[(wm + i * 16 + l16) * 32 + quad * 8]);
      afl[i] = *(const bhalf8*)(&AsL[(wm + i * 16 + l16) * 32 + quad * 8]);
      bgh[i] = *(const bhalf8*)(&BsH[(wn + i * 16 + l16) * 32 + quad * 8]);
      bgl[i] = *(const bhalf8*)(&BsL[(wn + i * 16 + l16) * 32 + quad * 8]);
    }
    #pragma unroll
    for (int i = 0; i < 4; ++i)
      #pragma unroll
      for (int j = 0; j < 4; ++j) {
        f32x4 a = acc[i][j];
        a = __builtin_amdgcn_mfma_f32_16x16x32_bf16(afh[i], bgh[j], a, 0, 0, 0);
        a = __builtin_amdgcn_mfma_f32_16x16x32_bf16(afh[i], bgl[j], a, 0, 0, 0);
        a = __builtin_amdgcn_mfma_f32_16x16x32_bf16(afl[i], bgh[j], a, 0, 0, 0);
        acc[i][j] = a;
      }
    __syncthreads();
  }

  // epilogue: C/D layout col=lane&15, row=quad*4+reg
  #pragma unroll
  for (int j = 0; j < 4; ++j) {
    const int n = bn + wn + j * 16 + l16;
    const float bv = bias[n];
    #pragma unroll
    for (int i = 0; i < 4; ++i)
      #pragma unroll
      for (int r = 0; r < 4; ++r) {
        const int m = bm + wm + i * 16 + quad * 4 + r;
        const float v = acc[i][j][r] + bv;
        if (OUTF32) {
          OutF[(size_t)m * Nn + n] = v;
        } else {
          unsigned short hh, ll;
          split2(v, hh, ll);
          OutH[(size_t)m * Nn + n] = hh;
          OutL[(size_t)m * Nn + n] = ll;
        }
      }
  }
}

// ---- RMSNorm over D=64 on q,k slices of the hi/lo qkv planes, in place ----
__global__ __launch_bounds__(256)
void rmsnorm_qk(unsigned short* __restrict__ H, unsigned short* __restrict__ L,
                const float* __restrict__ qn, const float* __restrict__ kn)
{
  const int rid  = blockIdx.x * 4 + (threadIdx.x >> 6);
  const int lane = threadIdx.x & 63;
  const int which = rid >> 16;          // 0=q, 1=k
  const int r2    = rid & 65535;
  const int token = r2 >> 4;
  const int h     = r2 & 15;

  const size_t base = (size_t)token * k3C + (size_t)which * kC + h * kD + lane;
  const float x = bf2f(H[base]) + bf2f(L[base]);
  float s = x * x;
  #pragma unroll
  for (int d = 32; d; d >>= 1) s += __shfl_xor(s, d, 64);
  const float rinv = rsqrtf(s * (1.0f / 64.0f) + 1e-6f);
  const float* w = which ? kn : qn;
  float y = w[lane] * (x * rinv);
  if (which == 0) y *= 0.125f;
  unsigned short hh, ll;
  split2(y, hh, ll);
  H[base] = hh; L[base] = ll;
}

// ---- flash attention; V from pre-transposed VT; all LDS padded stride 72 ----
__global__ __launch_bounds__(256)
void attn_kernel(unsigned short* __restrict__ H, unsigned short* __restrict__ L,
                 const unsigned short* __restrict__ VTH,
                 const unsigned short* __restrict__ VTL,
                 const int* __restrict__ mask)
{
  constexpr int P = 72;  // padded row stride (144B = 36 banks, 16B aligned)
  __shared__ __align__(16) unsigned short KtH[64 * P], KtL[64 * P]; // [key][d]
  __shared__ __align__(16) unsigned short VtH[64 * P], VtL[64 * P]; // [d][key]
  __shared__ __align__(16) float sflag[64];
  __shared__ __align__(16) unsigned short Pt[4][16 * P];            // [q][key]

  const int t    = threadIdx.x;
  const int wave = t >> 6;
  const int lane = t & 63;
  const int quad = lane >> 4;
  const int l16  = lane & 15;
  const int bh = blockIdx.y;
  const int b  = bh >> 4;
  const int h  = bh & 15;
  const int q0 = blockIdx.x * 64 + wave * 16;

  bhalf8 qfh[2], qfl[2];
  {
    const size_t qrow = (size_t)(b * kN + q0 + l16) * k3C + h * kD;
    qfh[0] = *(const bhalf8*)(&H[qrow + quad * 8]);
    qfh[1] = *(const bhalf8*)(&H[qrow + 32 + quad * 8]);
    qfl[0] = *(const bhalf8*)(&L[qrow + quad * 8]);
    qfl[1] = *(const bhalf8*)(&L[qrow + 32 + quad * 8]);
  }

  f32x4 acc_o[4] = {};
  float m_i[4], l_i[4];
  #pragma unroll
  for (int r = 0; r < 4; ++r) { m_i[r] = -1.0e9f; l_i[r] = 0.0f; }

  for (int kt = 0; kt < kN; kt += 64) {
    #pragma unroll
    for (int rr = 0; rr < 2; ++rr) {
      const int c   = rr * 256 + t;
      const int row = c >> 3;          // Kt: key; Vt: d
      const int col = (c & 7) * 8;     // Kt: d;   Vt: key
      const size_t kg = (size_t)(b * kN + kt + row) * k3C + kC + h * kD + col;
      *(uint4*)(&KtH[row * P + col]) = *(const uint4*)(&H[kg]);
      *(uint4*)(&KtL[row * P + col]) = *(const uint4*)(&L[kg]);
      const size_t vg = ((size_t)bh * kD + row) * kN + kt + col;
      *(uint4*)(&VtH[row * P + col]) = *(const uint4*)(&VTH[vg]);
      *(uint4*)(&VtL[row * P + col]) = *(const uint4*)(&VTL[vg]);
    }
    if (t < 64) sflag[t] = (mask[b * kN + kt + t] != 0) ? 1.0f : 0.0f;
    __syncthreads();

    // S = (Qh+Ql)(Kh+Kl)^T ~ QhKh + QhKl + QlKh
    f32x4 sacc[4];
    #pragma unroll
    for (int nt = 0; nt < 4; ++nt) {
      const int kr = (nt * 16 + l16) * P + quad * 8;
      bhalf8 bh0 = *(const bhalf8*)(&KtH[kr]);
      bhalf8 bh1 = *(const bhalf8*)(&KtH[kr + 32]);
      bhalf8 bl0 = *(const bhalf8*)(&KtL[kr]);
      bhalf8 bl1 = *(const bhalf8*)(&KtL[kr + 32]);
      f32x4 s = {};
      s = __builtin_amdgcn_mfma_f32_16x16x32_bf16(qfh[0], bh0, s, 0, 0, 0);
      s = __builtin_amdgcn_mfma_f32_16x16x32_bf16(qfh[1], bh1, s, 0, 0, 0);
      s = __builtin_amdgcn_mfma_f32_16x16x32_bf16(qfh[0], bl0, s, 0, 0, 0);
      s = __builtin_amdgcn_mfma_f32_16x16x32_bf16(qfh[1], bl1, s, 0, 0, 0);
      s = __builtin_amdgcn_mfma_f32_16x16x32_bf16(qfl[0], bh0, s, 0, 0, 0);
      s = __builtin_amdgcn_mfma_f32_16x16x32_bf16(qfl[1], bh1, s, 0, 0, 0);
      sacc[nt] = s;
    }

    // mask + online softmax (fp32)
    float p[4][4], rowmax[4];
    #pragma unroll
    for (int r = 0; r < 4; ++r) rowmax[r] = -1.0e9f;
    #pragma unroll
    for (int nt = 0; nt < 4; ++nt) {
      const float flag = sflag[nt * 16 + l16];
      #pragma unroll
      for (int r = 0; r < 4; ++r) {
        float s = sacc[nt][r];
        s = (flag != 0.0f) ? s : -1.0e9f;
        p[nt][r] = s;
        rowmax[r] = fmaxf(rowmax[r], s);
      }
    }
    #pragma unroll
    for (int r = 0; r < 4; ++r)
      #pragma unroll
      for (int d = 1; d < 16; d <<= 1)
        rowmax[r] = fmaxf(rowmax[r], __shfl_xor(rowmax[r], d, 64));

    float alpha[4];
    #pragma unroll
    for (int r = 0; r < 4; ++r) {
      const float mn = fmaxf(m_i[r], rowmax[r]);
      alpha[r] = safe_exp(m_i[r] - mn);
      m_i[r] = mn;
      float sum = 0.0f;
      #pragma unroll
      for (int nt = 0; nt < 4; ++nt) {
        const float e = safe_exp(p[nt][r] - mn);
        p[nt][r] = e;
        sum += e;
      }
      #pragma unroll
      for (int d = 1; d < 16; d <<= 1) sum += __shfl_xor(sum, d, 64);
      l_i[r] = l_i[r] * alpha[r] + sum;
      #pragma unroll
      for (int dt = 0; dt < 4; ++dt) acc_o[dt][r] *= alpha[r];
    }

    // P (C-layout) -> LDS (A-layout), bf16
    #pragma unroll
    for (int nt = 0; nt < 4; ++nt)
      #pragma unroll
      for (int r = 0; r < 4; ++r)
        Pt[wave][(quad * 4 + r) * P + nt * 16 + l16] = f2bf(p[nt][r]);
    __syncthreads();

    // O += P (Vh + Vl)
    #pragma unroll
    for (int kk = 0; kk < 2; ++kk) {
      bhalf8 pa = *(const bhalf8*)(&Pt[wave][l16 * P + kk * 32 + quad * 8]);
      #pragma unroll
      for (int dt = 0; dt < 4; ++dt) {
        const int vr = (dt * 16 + l16) * P + kk * 32 + quad * 8;
        bhalf8 vbh = *(const bhalf8*)(&VtH[vr]);
        bhalf8 vbl = *(const bhalf8*)(&VtL[vr]);
        acc_o[dt] = __builtin_amdgcn_mfma_f32_16x16x32_bf16(pa, vbh, acc_o[dt], 0, 0, 0);
        acc_o[dt] = __builtin_amdgcn_mfma_f32_16x16x32_bf16(pa, vbl, acc_o[dt], 0, 0, 0);
      }
    }
    __syncthreads();
  }

  // normalize + store hi/lo into q-slice
  #pragma unroll
  for (int dt = 0; dt < 4; ++dt)
    #pragma unroll
    for (int r = 0; r < 4; ++r) {
      const int qrow = q0 + quad * 4 + r;
      const float inv = 1.0f / fmaxf(l_i[r], 1.0e-30f);
      const size_t off = (size_t)(b * kN + qrow) * k3C + h * kD + dt * 16 + l16;
      unsigned short hh, ll;
      split2(acc_o[dt][r] * inv, hh, ll);
      H[off] = hh; L[off] = ll;
    }
}

} // anonymous namespace

extern "C" void kernel_launch(void* const* d_in, const int* in_sizes, int n_in,
                              void* d_out, int out_size, void* d_ws, size_t ws_size,
                              hipStream_t stream)
{
  const float* x      = (const float*)d_in[0];
  const int*   maskp  = (const int*)d_in[1];
  const float* qkv_w  = (const float*)d_in[2];
  const float* qkv_b  = (const float*)d_in[3];
  const float* proj_w = (const float*)d_in[4];
  const float* proj_b = (const float*)d_in[5];
  const float* qn_w   = (const float*)d_in[6];
  const float* kn_w   = (const float*)d_in[7];
  float* out = (float*)d_out;

  // workspace layout (u16 units), total 79.7 MB with region reuse:
  unsigned short* qH = (unsigned short*)d_ws;      // qkv hi plane
  unsigned short* qL = qH + kPS;                   // qkv lo plane
  unsigned short* R1 = qL + kPS;                   // x planes -> later VT planes
  unsigned short* R2 = R1 + 2 * kXE;               // qkv_w planes -> later proj_w planes
  unsigned short* xH = R1,  *xL = R1 + kXE;
  unsigned short* VTH = R1, *VTL = R1 + kXE;       // reuse after gemm1
  unsigned short* wqH = R2, *wqL = R2 + kWQ;
  unsigned short* wpH = R2, *wpL = R2 + kWP;       // reuse after gemm1

  // pre-split fp32 -> hi/lo planes
  split_planes<<<(int)(kXE / 4 / 256), 256, 0, stream>>>(x, xH, xL, (int)(kXE / 4));
  split_planes<<<(int)(kWQ / 4 / 256), 256, 0, stream>>>(qkv_w, wqH, wqL, (int)(kWQ / 4));

  // 1) qkv = x @ qkv_w^T + qkv_b  (planes out)
  gemm_planes<false><<<dim3(kTok / 128, k3C / 128), 256, 0, stream>>>(
      xH, xL, kC, wqH, wqL, qkv_b, nullptr, qH, qL, k3C, kC);

  // 2) RMSNorm q,k (q also * 1/8)
  rmsnorm_qk<<<(2 * kTok * kH) / 4, 256, 0, stream>>>(qH, qL, qn_w, kn_w);

  // 3a) pre-transpose V into VT (overwrites x planes: no longer needed)
  vt_transpose<<<2048, 256, 0, stream>>>(qH, qL, VTH, VTL);

  // 3b) pre-split proj_w (overwrites qkv_w planes: no longer needed)
  split_planes<<<(int)(kWP / 4 / 256), 256, 0, stream>>>(proj_w, wpH, wpL, (int)(kWP / 4));

  // 3c) masked flash attention; result into q-slice of planes
  attn_kernel<<<dim3(kN / 64, kB * kH), 256, 0, stream>>>(qH, qL, VTH, VTL, maskp);

  // 4) out = attn @ proj_w^T + proj_b  (fp32 out); A = q-slice, lda=3072
  gemm_planes<true><<<dim3(kTok / 128, kC / 128), 256, 0, stream>>>(
      qH, qL, k3C, wpH, wpL, proj_b, out, nullptr, nullptr, kC, kC);
}

// Round 5
// 390.376 us; speedup vs baseline: 1.4924x; 1.1339x over previous
//
#include <hip/hip_runtime.h>
#include <hip/hip_bf16.h>
#include <stdint.h>

namespace {

constexpr int kB = 2;
constexpr int kN = 2048;
constexpr int kC = 1024;
constexpr int kH = 16;
constexpr int kD = 64;
constexpr int kTok = kB * kN;               // 4096
constexpr int k3C  = 3 * kC;                // 3072
constexpr size_t kPS = (size_t)kTok * k3C;  // qkv plane elems
constexpr size_t kXE = (size_t)kTok * kC;   // x / VT plane elems
constexpr size_t kWQ = (size_t)k3C * kC;    // qkv_w elems
constexpr size_t kWP = (size_t)kC * kC;     // proj_w elems

using bhalf8 = __attribute__((ext_vector_type(8))) __bf16;
using f32x4  = __attribute__((ext_vector_type(4))) float;

__device__ inline unsigned short f2bf(float f) {
  __hip_bfloat16 h = __float2bfloat16(f);
  return *reinterpret_cast<unsigned short*>(&h);
}
__device__ inline float bf2f(unsigned short u) {
  __hip_bfloat16 h;
  *reinterpret_cast<unsigned short*>(&h) = u;
  return __bfloat162float(h);
}
__device__ inline void split2(float v, unsigned short& h, unsigned short& l) {
  const unsigned short hb = f2bf(v);
  h = hb;
  l = f2bf(v - bf2f(hb));
}

// async global->LDS, 16B per lane; LDS dest must be wave-uniform base + lane*16
__device__ inline void glds16(const unsigned short* g, unsigned short* l) {
  __builtin_amdgcn_global_load_lds(
      (const __attribute__((address_space(1))) void*)g,
      (__attribute__((address_space(3))) void*)l, 16, 0, 0);
}

// ---- split fp32 -> bf16 hi/lo planes ----
__global__ __launch_bounds__(256)
void split_planes(const float* __restrict__ src,
                  unsigned short* __restrict__ H,
                  unsigned short* __restrict__ L, int n4)
{
  const int i = blockIdx.x * 256 + threadIdx.x;
  if (i >= n4) return;
  const float4 v = ((const float4*)src)[i];
  ushort4 hh, ll;
  split2(v.x, hh.x, ll.x); split2(v.y, hh.y, ll.y);
  split2(v.z, hh.z, ll.z); split2(v.w, hh.w, ll.w);
  ((ushort4*)H)[i] = hh;
  ((ushort4*)L)[i] = ll;
}

// ---- pre-transpose V slice of qkv planes into VT[bh][d][token] ----
__global__ __launch_bounds__(256)
void vt_transpose(const unsigned short* __restrict__ H,
                  const unsigned short* __restrict__ L,
                  unsigned short* __restrict__ VTH,
                  unsigned short* __restrict__ VTL)
{
  const int gw   = blockIdx.x * 4 + (threadIdx.x >> 6);  // 0..8191
  const int lane = threadIdx.x & 63;                     // = d
  const int bh   = gw >> 8;
  const int oct  = gw & 255;
  const int b = bh >> 4, h = bh & 15;
  const int tok0 = oct * 8;
  union { unsigned short u[8]; uint4 v; } ph, pl;
  #pragma unroll
  for (int e = 0; e < 8; ++e) {
    const size_t g = (size_t)(b * kN + tok0 + e) * k3C + 2 * kC + h * kD + lane;
    ph.u[e] = H[g];
    pl.u[e] = L[g];
  }
  const size_t o = ((size_t)bh * kD + lane) * kN + tok0;
  *(uint4*)(&VTH[o]) = ph.v;
  *(uint4*)(&VTL[o]) = pl.v;
}

// ---- plane GEMM: C = (AH+AL) @ (WH+WL)^T + bias; 3-term MFMA; m97 staging ----
// FUSE_NORM: apply per-head (D=64) RMSNorm to q,k slices in the epilogue
// (each wave's 64-col span = exactly one head; q also gets * D^-0.5).
template<bool OUTF32, bool FUSE_NORM>
__global__ __launch_bounds__(256)
void gemm_planes(const unsigned short* __restrict__ AH,
                 const unsigned short* __restrict__ AL, int lda,
                 const unsigned short* __restrict__ WH,
                 const unsigned short* __restrict__ WL,
                 const float* __restrict__ bias,
                 float* __restrict__ OutF,
                 unsigned short* __restrict__ OutH,
                 unsigned short* __restrict__ OutL,
                 const float* __restrict__ qn,
                 const float* __restrict__ kn,
                 int Nn, int K)
{
  __shared__ __align__(16) unsigned short AsH[128 * 32], AsL[128 * 32];
  __shared__ __align__(16) unsigned short BsH[128 * 32], BsL[128 * 32];

  const int t    = threadIdx.x;
  const int wave = t >> 6;
  const int lane = t & 63;
  const int quad = lane >> 4;
  const int l16  = lane & 15;
  const int bm = blockIdx.x * 128;
  const int bn = blockIdx.y * 128;
  const int wm = (wave >> 1) * 64;
  const int wn = (wave & 1) * 64;

  f32x4 acc[4][4] = {};

  for (int k0 = 0; k0 < K; k0 += 32) {
    #pragma unroll
    for (int r = 0; r < 2; ++r) {
      const int c   = r * 256 + t;
      const int row = c >> 2;
      const int col = (c & 3) * 8;
      glds16(&AH[(size_t)(bm + row) * lda + k0 + col], &AsH[c * 8]);
      glds16(&AL[(size_t)(bm + row) * lda + k0 + col], &AsL[c * 8]);
      glds16(&WH[(size_t)(bn + row) * K + k0 + col], &BsH[c * 8]);
      glds16(&WL[(size_t)(bn + row) * K + k0 + col], &BsL[c * 8]);
    }
    __syncthreads();

    bhalf8 afh[4], afl[4], bgh[4], bgl[4];
    #pragma unroll
    for (int i = 0; i < 4; ++i) {
      afh[i] = *(const bhalf8*)(&AsH[(wm + i * 16 + l16) * 32 + quad * 8]);
      afl[i] = *(const bhalf8*)(&AsL[(wm + i * 16 + l16) * 32 + quad * 8]);
      bgh[i] = *(const bhalf8*)(&BsH[(wn + i * 16 + l16) * 32 + quad * 8]);
      bgl[i] = *(const bhalf8*)(&BsL[(wn + i * 16 + l16) * 32 + quad * 8]);
    }
    #pragma unroll
    for (int i = 0; i < 4; ++i)
      #pragma unroll
      for (int j = 0; j < 4; ++j) {
        f32x4 a = acc[i][j];
        a = __builtin_amdgcn_mfma_f32_16x16x32_bf16(afh[i], bgh[j], a, 0, 0, 0);
        a = __builtin_amdgcn_mfma_f32_16x16x32_bf16(afh[i], bgl[j], a, 0, 0, 0);
        a = __builtin_amdgcn_mfma_f32_16x16x32_bf16(afl[i], bgh[j], a, 0, 0, 0);
        acc[i][j] = a;
      }
    __syncthreads();
  }

  // epilogue: C/D layout col=lane&15, row=quad*4+reg
  float bv[4], wv[4];
  const int slice = FUSE_NORM ? (bn >> 10) : 2;   // 0=q,1=k,2=v (128 | 1024 -> uniform)
  #pragma unroll
  for (int j = 0; j < 4; ++j) {
    bv[j] = bias[bn + wn + j * 16 + l16];
    if (FUSE_NORM && slice < 2)
      wv[j] = (slice ? kn : qn)[j * 16 + l16];    // d = (n & 63) = j*16+l16
  }

  #pragma unroll
  for (int i = 0; i < 4; ++i) {
    float val[4][4];
    #pragma unroll
    for (int j = 0; j < 4; ++j)
      #pragma unroll
      for (int r = 0; r < 4; ++r)
        val[j][r] = acc[i][j][r] + bv[j];

    if (FUSE_NORM && slice < 2) {
      #pragma unroll
      for (int r = 0; r < 4; ++r) {
        float ss = val[0][r] * val[0][r];
        #pragma unroll
        for (int j = 1; j < 4; ++j) ss += val[j][r] * val[j][r];
        #pragma unroll
        for (int d = 1; d < 16; d <<= 1) ss += __shfl_xor(ss, d, 64); // intra-quad
        float rinv = rsqrtf(ss * (1.0f / 64.0f) + 1e-6f);
        if (slice == 0) rinv *= 0.125f;           // q * D^-0.5
        #pragma unroll
        for (int j = 0; j < 4; ++j) val[j][r] = wv[j] * (val[j][r] * rinv);
      }
    }

    #pragma unroll
    for (int j = 0; j < 4; ++j) {
      const int n = bn + wn + j * 16 + l16;
      #pragma unroll
      for (int r = 0; r < 4; ++r) {
        const int m = bm + wm + i * 16 + quad * 4 + r;
        if (OUTF32) {
          OutF[(size_t)m * Nn + n] = val[j][r];
        } else {
          unsigned short hh, ll;
          split2(val[j][r], hh, ll);
          OutH[(size_t)m * Nn + n] = hh;
          OutL[(size_t)m * Nn + n] = ll;
        }
      }
    }
  }
}

// ---- flash attention, static-max softmax ----
// After RMSNorm: |q_row|=1 (norm 1 * 0.125 * sqrt(64)), |k_row|<=8 => |S|<=8.01.
// exp(S) <= 3010, row sum <= 6.2e6: no overflow, so no online max needed.
__global__ __launch_bounds__(256)
void attn_kernel(unsigned short* __restrict__ H, unsigned short* __restrict__ L,
                 const unsigned short* __restrict__ VTH,
                 const unsigned short* __restrict__ VTL,
                 const int* __restrict__ mask)
{
  constexpr int P = 72;  // 144B stride: 16B-aligned, 2-way bank aliasing only (free)
  __shared__ __align__(16) unsigned short KtH[64 * P], KtL[64 * P]; // [key][d]
  __shared__ __align__(16) unsigned short VtH[64 * P], VtL[64 * P]; // [d][key]
  __shared__ __align__(16) float sflag[64];
  __shared__ __align__(16) unsigned short Pt[4][16 * P];            // per-wave [q][key]

  const int t    = threadIdx.x;
  const int wave = t >> 6;
  const int lane = t & 63;
  const int quad = lane >> 4;
  const int l16  = lane & 15;
  const int bh = blockIdx.y;
  const int b  = bh >> 4;
  const int h  = bh & 15;
  const int q0 = blockIdx.x * 64 + wave * 16;

  bhalf8 qfh[2], qfl[2];
  {
    const size_t qrow = (size_t)(b * kN + q0 + l16) * k3C + h * kD;
    qfh[0] = *(const bhalf8*)(&H[qrow + quad * 8]);
    qfh[1] = *(const bhalf8*)(&H[qrow + 32 + quad * 8]);
    qfl[0] = *(const bhalf8*)(&L[qrow + quad * 8]);
    qfl[1] = *(const bhalf8*)(&L[qrow + 32 + quad * 8]);
  }

  f32x4 acc_o[4] = {};
  float l_i[4] = {0.0f, 0.0f, 0.0f, 0.0f};

  for (int kt = 0; kt < kN; kt += 64) {
    #pragma unroll
    for (int rr = 0; rr < 2; ++rr) {
      const int c   = rr * 256 + t;
      const int row = c >> 3;
      const int col = (c & 7) * 8;
      const size_t kg = (size_t)(b * kN + kt + row) * k3C + kC + h * kD + col;
      *(uint4*)(&KtH[row * P + col]) = *(const uint4*)(&H[kg]);
      *(uint4*)(&KtL[row * P + col]) = *(const uint4*)(&L[kg]);
      const size_t vg = ((size_t)bh * kD + row) * kN + kt + col;
      *(uint4*)(&VtH[row * P + col]) = *(const uint4*)(&VTH[vg]);
      *(uint4*)(&VtL[row * P + col]) = *(const uint4*)(&VTL[vg]);
    }
    if (t < 64) sflag[t] = (mask[b * kN + kt + t] != 0) ? 1.0f : 0.0f;
    __syncthreads();

    // S = (Qh+Ql)(Kh+Kl)^T ~ QhKh + QhKl + QlKh
    f32x4 sacc[4];
    #pragma unroll
    for (int nt = 0; nt < 4; ++nt) {
      const int kr = (nt * 16 + l16) * P + quad * 8;
      bhalf8 bh0 = *(const bhalf8*)(&KtH[kr]);
      bhalf8 bh1 = *(const bhalf8*)(&KtH[kr + 32]);
      bhalf8 bl0 = *(const bhalf8*)(&KtL[kr]);
      bhalf8 bl1 = *(const bhalf8*)(&KtL[kr + 32]);
      f32x4 s = {};
      s = __builtin_amdgcn_mfma_f32_16x16x32_bf16(qfh[0], bh0, s, 0, 0, 0);
      s = __builtin_amdgcn_mfma_f32_16x16x32_bf16(qfh[1], bh1, s, 0, 0, 0);
      s = __builtin_amdgcn_mfma_f32_16x16x32_bf16(qfh[0], bl0, s, 0, 0, 0);
      s = __builtin_amdgcn_mfma_f32_16x16x32_bf16(qfh[1], bl1, s, 0, 0, 0);
      s = __builtin_amdgcn_mfma_f32_16x16x32_bf16(qfl[0], bh0, s, 0, 0, 0);
      s = __builtin_amdgcn_mfma_f32_16x16x32_bf16(qfl[1], bh1, s, 0, 0, 0);
      sacc[nt] = s;
    }

    // static-max softmax: p = flag * exp(s); accumulate row sums
    float srow[4] = {0.0f, 0.0f, 0.0f, 0.0f};
    #pragma unroll
    for (int nt = 0; nt < 4; ++nt) {
      const float flag = sflag[nt * 16 + l16];
      #pragma unroll
      for (int r = 0; r < 4; ++r) {
        const float p = flag * __expf(sacc[nt][r]);   // s in [-8.01, 8.01]
        srow[r] += p;
        Pt[wave][(quad * 4 + r) * P + nt * 16 + l16] = f2bf(p);
      }
    }
    #pragma unroll
    for (int r = 0; r < 4; ++r) {
      #pragma unroll
      for (int d = 1; d < 16; d <<= 1) srow[r] += __shfl_xor(srow[r], d, 64);
      l_i[r] += srow[r];
    }

    // NO barrier here: Pt is per-wave scratch; same-wave lgkmcnt orders write->read

    // O += P (Vh + Vl)
    #pragma unroll
    for (int kk = 0; kk < 2; ++kk) {
      bhalf8 pa = *(const bhalf8*)(&Pt[wave][l16 * P + kk * 32 + quad * 8]);
      #pragma unroll
      for (int dt = 0; dt < 4; ++dt) {
        const int vr = (dt * 16 + l16) * P + kk * 32 + quad * 8;
        bhalf8 vbh = *(const bhalf8*)(&VtH[vr]);
        bhalf8 vbl = *(const bhalf8*)(&VtL[vr]);
        acc_o[dt] = __builtin_amdgcn_mfma_f32_16x16x32_bf16(pa, vbh, acc_o[dt], 0, 0, 0);
        acc_o[dt] = __builtin_amdgcn_mfma_f32_16x16x32_bf16(pa, vbl, acc_o[dt], 0, 0, 0);
      }
    }
    __syncthreads();
  }

  // normalize + store hi/lo into q-slice
  #pragma unroll
  for (int dt = 0; dt < 4; ++dt)
    #pragma unroll
    for (int r = 0; r < 4; ++r) {
      const int qrow = q0 + quad * 4 + r;
      const float inv = 1.0f / fmaxf(l_i[r], 1.0e-30f);
      const size_t off = (size_t)(b * kN + qrow) * k3C + h * kD + dt * 16 + l16;
      unsigned short hh, ll;
      split2(acc_o[dt][r] * inv, hh, ll);
      H[off] = hh; L[off] = ll;
    }
}

} // anonymous namespace

extern "C" void kernel_launch(void* const* d_in, const int* in_sizes, int n_in,
                              void* d_out, int out_size, void* d_ws, size_t ws_size,
                              hipStream_t stream)
{
  const float* x      = (const float*)d_in[0];
  const int*   maskp  = (const int*)d_in[1];
  const float* qkv_w  = (const float*)d_in[2];
  const float* qkv_b  = (const float*)d_in[3];
  const float* proj_w = (const float*)d_in[4];
  const float* proj_b = (const float*)d_in[5];
  const float* qn_w   = (const float*)d_in[6];
  const float* kn_w   = (const float*)d_in[7];
  float* out = (float*)d_out;

  unsigned short* qH = (unsigned short*)d_ws;      // qkv hi plane
  unsigned short* qL = qH + kPS;                   // qkv lo plane
  unsigned short* R1 = qL + kPS;                   // x planes -> later VT planes
  unsigned short* R2 = R1 + 2 * kXE;               // qkv_w planes -> later proj_w planes
  unsigned short* xH = R1,  *xL = R1 + kXE;
  unsigned short* VTH = R1, *VTL = R1 + kXE;
  unsigned short* wqH = R2, *wqL = R2 + kWQ;
  unsigned short* wpH = R2, *wpL = R2 + kWP;

  split_planes<<<(int)(kXE / 4 / 256), 256, 0, stream>>>(x, xH, xL, (int)(kXE / 4));
  split_planes<<<(int)(kWQ / 4 / 256), 256, 0, stream>>>(qkv_w, wqH, wqL, (int)(kWQ / 4));

  // 1) qkv = x @ qkv_w^T + qkv_b, RMSNorm(q,k) fused into epilogue
  gemm_planes<false, true><<<dim3(kTok / 128, k3C / 128), 256, 0, stream>>>(
      xH, xL, kC, wqH, wqL, qkv_b, nullptr, qH, qL, qn_w, kn_w, k3C, kC);

  // 2) pre-transpose V (overwrites x planes) ; pre-split proj_w (overwrites qkv_w)
  vt_transpose<<<2048, 256, 0, stream>>>(qH, qL, VTH, VTL);
  split_planes<<<(int)(kWP / 4 / 256), 256, 0, stream>>>(proj_w, wpH, wpL, (int)(kWP / 4));

  // 3) masked flash attention; result into q-slice of planes
  attn_kernel<<<dim3(kN / 64, kB * kH), 256, 0, stream>>>(qH, qL, VTH, VTL, maskp);

  // 4) out = attn @ proj_w^T + proj_b
  gemm_planes<true, false><<<dim3(kTok / 128, kC / 128), 256, 0, stream>>>(
      qH, qL, k3C, wpH, wpL, proj_b, out, nullptr, nullptr, nullptr, nullptr, kC, kC);
}

// Round 6
// 380.973 us; speedup vs baseline: 1.5293x; 1.0247x over previous
//
#include <hip/hip_runtime.h>
#include <hip/hip_bf16.h>
#include <stdint.h>

namespace {

constexpr int kB = 2;
constexpr int kN = 2048;
constexpr int kC = 1024;
constexpr int kH = 16;
constexpr int kD = 64;
constexpr int kTok = kB * kN;               // 4096
constexpr int k3C  = 3 * kC;                // 3072
constexpr size_t kPS = (size_t)kTok * k3C;  // qkv plane elems
constexpr size_t kXE = (size_t)kTok * kC;   // x / VT plane elems
constexpr size_t kWQ = (size_t)k3C * kC;    // qkv_w elems
constexpr size_t kWP = (size_t)kC * kC;     // proj_w elems

using bhalf8 = __attribute__((ext_vector_type(8))) __bf16;
using f32x4  = __attribute__((ext_vector_type(4))) float;

__device__ inline unsigned short f2bf(float f) {
  __hip_bfloat16 h = __float2bfloat16(f);
  return *reinterpret_cast<unsigned short*>(&h);
}
__device__ inline float bf2f(unsigned short u) {
  __hip_bfloat16 h;
  *reinterpret_cast<unsigned short*>(&h) = u;
  return __bfloat162float(h);
}
__device__ inline void split2(float v, unsigned short& h, unsigned short& l) {
  const unsigned short hb = f2bf(v);
  h = hb;
  l = f2bf(v - bf2f(hb));
}

// async global->LDS, 16B per lane; LDS dest must be wave-uniform base + lane*16
__device__ inline void glds16(const unsigned short* g, unsigned short* l) {
  __builtin_amdgcn_global_load_lds(
      (const __attribute__((address_space(1))) void*)g,
      (__attribute__((address_space(3))) void*)l, 16, 0, 0);
}

// ---- split fp32 -> bf16 hi/lo planes ----
__global__ __launch_bounds__(256)
void split_planes(const float* __restrict__ src,
                  unsigned short* __restrict__ H,
                  unsigned short* __restrict__ L, int n4)
{
  const int i = blockIdx.x * 256 + threadIdx.x;
  if (i >= n4) return;
  const float4 v = ((const float4*)src)[i];
  ushort4 hh, ll;
  split2(v.x, hh.x, ll.x); split2(v.y, hh.y, ll.y);
  split2(v.z, hh.z, ll.z); split2(v.w, hh.w, ll.w);
  ((ushort4*)H)[i] = hh;
  ((ushort4*)L)[i] = ll;
}

// ---- pre-transpose V slice of qkv planes into VT[bh][d][token] ----
__global__ __launch_bounds__(256)
void vt_transpose(const unsigned short* __restrict__ H,
                  const unsigned short* __restrict__ L,
                  unsigned short* __restrict__ VTH,
                  unsigned short* __restrict__ VTL)
{
  const int gw   = blockIdx.x * 4 + (threadIdx.x >> 6);  // 0..8191
  const int lane = threadIdx.x & 63;                     // = d
  const int bh   = gw >> 8;
  const int oct  = gw & 255;
  const int b = bh >> 4, h = bh & 15;
  const int tok0 = oct * 8;
  union { unsigned short u[8]; uint4 v; } ph, pl;
  #pragma unroll
  for (int e = 0; e < 8; ++e) {
    const size_t g = (size_t)(b * kN + tok0 + e) * k3C + 2 * kC + h * kD + lane;
    ph.u[e] = H[g];
    pl.u[e] = L[g];
  }
  const size_t o = ((size_t)bh * kD + lane) * kN + tok0;
  *(uint4*)(&VTH[o]) = ph.v;
  *(uint4*)(&VTL[o]) = pl.v;
}

// ---- plane GEMM: C = (AH+AL) @ (WH+WL)^T + bias; 3-term MFMA; m97 staging ----
template<bool OUTF32, bool FUSE_NORM>
__global__ __launch_bounds__(256)
void gemm_planes(const unsigned short* __restrict__ AH,
                 const unsigned short* __restrict__ AL, int lda,
                 const unsigned short* __restrict__ WH,
                 const unsigned short* __restrict__ WL,
                 const float* __restrict__ bias,
                 float* __restrict__ OutF,
                 unsigned short* __restrict__ OutH,
                 unsigned short* __restrict__ OutL,
                 const float* __restrict__ qn,
                 const float* __restrict__ kn,
                 int Nn, int K)
{
  __shared__ __align__(16) unsigned short AsH[128 * 32], AsL[128 * 32];
  __shared__ __align__(16) unsigned short BsH[128 * 32], BsL[128 * 32];

  const int t    = threadIdx.x;
  const int wave = t >> 6;
  const int lane = t & 63;
  const int quad = lane >> 4;
  const int l16  = lane & 15;
  const int bm = blockIdx.x * 128;
  const int bn = blockIdx.y * 128;
  const int wm = (wave >> 1) * 64;
  const int wn = (wave & 1) * 64;

  f32x4 acc[4][4] = {};

  for (int k0 = 0; k0 < K; k0 += 32) {
    #pragma unroll
    for (int r = 0; r < 2; ++r) {
      const int c   = r * 256 + t;
      const int row = c >> 2;
      const int col = (c & 3) * 8;
      glds16(&AH[(size_t)(bm + row) * lda + k0 + col], &AsH[c * 8]);
      glds16(&AL[(size_t)(bm + row) * lda + k0 + col], &AsL[c * 8]);
      glds16(&WH[(size_t)(bn + row) * K + k0 + col], &BsH[c * 8]);
      glds16(&WL[(size_t)(bn + row) * K + k0 + col], &BsL[c * 8]);
    }
    __syncthreads();

    bhalf8 afh[4], afl[4], bgh[4], bgl[4];
    #pragma unroll
    for (int i = 0; i < 4; ++i) {
      afh[i] = *(const bhalf8*)(&AsH[(wm + i * 16 + l16) * 32 + quad * 8]);
      afl[i] = *(const bhalf8*)(&AsL[(wm + i * 16 + l16) * 32 + quad * 8]);
      bgh[i] = *(const bhalf8*)(&BsH[(wn + i * 16 + l16) * 32 + quad * 8]);
      bgl[i] = *(const bhalf8*)(&BsL[(wn + i * 16 + l16) * 32 + quad * 8]);
    }
    #pragma unroll
    for (int i = 0; i < 4; ++i)
      #pragma unroll
      for (int j = 0; j < 4; ++j) {
        f32x4 a = acc[i][j];
        a = __builtin_amdgcn_mfma_f32_16x16x32_bf16(afh[i], bgh[j], a, 0, 0, 0);
        a = __builtin_amdgcn_mfma_f32_16x16x32_bf16(afh[i], bgl[j], a, 0, 0, 0);
        a = __builtin_amdgcn_mfma_f32_16x16x32_bf16(afl[i], bgh[j], a, 0, 0, 0);
        acc[i][j] = a;
      }
    __syncthreads();
  }

  // epilogue: C/D layout col=lane&15, row=quad*4+reg
  float bv[4], wv[4];
  const int slice = FUSE_NORM ? (bn >> 10) : 2;   // 0=q,1=k,2=v
  #pragma unroll
  for (int j = 0; j < 4; ++j) {
    bv[j] = bias[bn + wn + j * 16 + l16];
    if (FUSE_NORM && slice < 2)
      wv[j] = (slice ? kn : qn)[j * 16 + l16];    // d = j*16+l16
  }

  #pragma unroll
  for (int i = 0; i < 4; ++i) {
    float val[4][4];
    #pragma unroll
    for (int j = 0; j < 4; ++j)
      #pragma unroll
      for (int r = 0; r < 4; ++r)
        val[j][r] = acc[i][j][r] + bv[j];

    if (FUSE_NORM && slice < 2) {
      #pragma unroll
      for (int r = 0; r < 4; ++r) {
        float ss = val[0][r] * val[0][r];
        #pragma unroll
        for (int j = 1; j < 4; ++j) ss += val[j][r] * val[j][r];
        #pragma unroll
        for (int d = 1; d < 16; d <<= 1) ss += __shfl_xor(ss, d, 64);
        float rinv = rsqrtf(ss * (1.0f / 64.0f) + 1e-6f);
        if (slice == 0) rinv *= 0.125f;           // q * D^-0.5
        #pragma unroll
        for (int j = 0; j < 4; ++j) val[j][r] = wv[j] * (val[j][r] * rinv);
      }
    }

    #pragma unroll
    for (int j = 0; j < 4; ++j) {
      const int n = bn + wn + j * 16 + l16;
      #pragma unroll
      for (int r = 0; r < 4; ++r) {
        const int m = bm + wm + i * 16 + quad * 4 + r;
        if (OUTF32) {
          OutF[(size_t)m * Nn + n] = val[j][r];
        } else {
          unsigned short hh, ll;
          split2(val[j][r], hh, ll);
          OutH[(size_t)m * Nn + n] = hh;
          OutL[(size_t)m * Nn + n] = ll;
        }
      }
    }
  }
}

// ---- flash attention, static-max softmax, 32 q-rows/wave, pipelined staging ----
// |S| <= 8.01 (|q_row|=1 after norm*scale, |k_row|<=8): exp safe without max.
__global__ __launch_bounds__(256)
void attn_kernel(unsigned short* __restrict__ H, unsigned short* __restrict__ L,
                 const unsigned short* __restrict__ VTH,
                 const unsigned short* __restrict__ VTL,
                 const int* __restrict__ mask)
{
  constexpr int P = 72;  // 144B stride: 16B-aligned rows, fragment reads conflict-free
  __shared__ __align__(16) unsigned short KtH[64 * P], KtL[64 * P]; // [key][d]
  __shared__ __align__(16) unsigned short VtH[64 * P], VtL[64 * P]; // [d][key]
  __shared__ __align__(16) float sflag[64];
  __shared__ __align__(16) unsigned short Pt[4][32 * P];            // per-wave [q][key]

  const int t    = threadIdx.x;
  const int wave = t >> 6;
  const int lane = t & 63;
  const int quad = lane >> 4;
  const int l16  = lane & 15;
  const int bh = blockIdx.y;
  const int b  = bh >> 4;
  const int h  = bh & 15;
  const int q0 = blockIdx.x * 128 + wave * 32;   // 32 q-rows per wave, 2 groups of 16

  // Q fragments for both row groups (A-layout: m=l16, k=quad*8+j)
  bhalf8 qfh[2][2], qfl[2][2];
  #pragma unroll
  for (int g = 0; g < 2; ++g) {
    const size_t qrow = (size_t)(b * kN + q0 + g * 16 + l16) * k3C + h * kD;
    qfh[g][0] = *(const bhalf8*)(&H[qrow + quad * 8]);
    qfh[g][1] = *(const bhalf8*)(&H[qrow + 32 + quad * 8]);
    qfl[g][0] = *(const bhalf8*)(&L[qrow + quad * 8]);
    qfl[g][1] = *(const bhalf8*)(&L[qrow + 32 + quad * 8]);
  }

  f32x4 acc_o[2][4] = {};
  float l_i[2][4] = {};

  // register prefetch pipeline for K/V staging
  const int prow = t >> 3;          // 0..31 (+32 for rr=1)
  const int pcol = (t & 7) * 8;
  uint4 pkh[2], pkl[2], pvh[2], pvl[2];
  float flagv = 0.0f;

  auto prefetch = [&](int kt) {
    #pragma unroll
    for (int rr = 0; rr < 2; ++rr) {
      const int row = rr * 32 + prow;
      const size_t kg = (size_t)(b * kN + kt + row) * k3C + kC + h * kD + pcol;
      pkh[rr] = *(const uint4*)(&H[kg]);
      pkl[rr] = *(const uint4*)(&L[kg]);
      const size_t vg = ((size_t)bh * kD + row) * kN + kt + pcol;
      pvh[rr] = *(const uint4*)(&VTH[vg]);
      pvl[rr] = *(const uint4*)(&VTL[vg]);
    }
    if (t < 64) flagv = (mask[b * kN + kt + t] != 0) ? 1.0f : 0.0f;
  };

  prefetch(0);

  for (int kt = 0; kt < kN; kt += 64) {
    // drain prefetched regs into LDS
    #pragma unroll
    for (int rr = 0; rr < 2; ++rr) {
      const int row = rr * 32 + prow;
      *(uint4*)(&KtH[row * P + pcol]) = pkh[rr];
      *(uint4*)(&KtL[row * P + pcol]) = pkl[rr];
      *(uint4*)(&VtH[row * P + pcol]) = pvh[rr];
      *(uint4*)(&VtL[row * P + pcol]) = pvl[rr];
    }
    if (t < 64) sflag[t] = flagv;
    __syncthreads();

    // issue next tile's global loads; latency hides under MFMA below
    if (kt + 64 < kN) prefetch(kt + 64);

    // S + elementwise softmax fused per nt (no row-max needed)
    float srow[2][4] = {};
    #pragma unroll
    for (int nt = 0; nt < 4; ++nt) {
      const int kr = (nt * 16 + l16) * P + quad * 8;
      const bhalf8 bh0 = *(const bhalf8*)(&KtH[kr]);
      const bhalf8 bh1 = *(const bhalf8*)(&KtH[kr + 32]);
      const bhalf8 bl0 = *(const bhalf8*)(&KtL[kr]);
      const bhalf8 bl1 = *(const bhalf8*)(&KtL[kr + 32]);
      const float flag = sflag[nt * 16 + l16];
      #pragma unroll
      for (int g = 0; g < 2; ++g) {
        f32x4 s = {};
        s = __builtin_amdgcn_mfma_f32_16x16x32_bf16(qfh[g][0], bh0, s, 0, 0, 0);
        s = __builtin_amdgcn_mfma_f32_16x16x32_bf16(qfh[g][1], bh1, s, 0, 0, 0);
        s = __builtin_amdgcn_mfma_f32_16x16x32_bf16(qfh[g][0], bl0, s, 0, 0, 0);
        s = __builtin_amdgcn_mfma_f32_16x16x32_bf16(qfh[g][1], bl1, s, 0, 0, 0);
        s = __builtin_amdgcn_mfma_f32_16x16x32_bf16(qfl[g][0], bh0, s, 0, 0, 0);
        s = __builtin_amdgcn_mfma_f32_16x16x32_bf16(qfl[g][1], bh1, s, 0, 0, 0);
        #pragma unroll
        for (int r = 0; r < 4; ++r) {
          const float p = flag * __expf(s[r]);
          srow[g][r] += p;
          Pt[wave][(g * 16 + quad * 4 + r) * P + nt * 16 + l16] = f2bf(p);
        }
      }
    }
    #pragma unroll
    for (int g = 0; g < 2; ++g)
      #pragma unroll
      for (int r = 0; r < 4; ++r) {
        float s = srow[g][r];
        #pragma unroll
        for (int d = 1; d < 16; d <<= 1) s += __shfl_xor(s, d, 64);
        l_i[g][r] += s;
      }

    // NO barrier: Pt is per-wave; same-wave DS ordering + lgkmcnt suffice

    // O += P (Vh + Vl); V fragments shared across both groups
    #pragma unroll
    for (int kk = 0; kk < 2; ++kk) {
      const bhalf8 pa0 = *(const bhalf8*)(&Pt[wave][l16 * P + kk * 32 + quad * 8]);
      const bhalf8 pa1 = *(const bhalf8*)(&Pt[wave][(16 + l16) * P + kk * 32 + quad * 8]);
      #pragma unroll
      for (int dt = 0; dt < 4; ++dt) {
        const int vr = (dt * 16 + l16) * P + kk * 32 + quad * 8;
        const bhalf8 vbh = *(const bhalf8*)(&VtH[vr]);
        const bhalf8 vbl = *(const bhalf8*)(&VtL[vr]);
        acc_o[0][dt] = __builtin_amdgcn_mfma_f32_16x16x32_bf16(pa0, vbh, acc_o[0][dt], 0, 0, 0);
        acc_o[0][dt] = __builtin_amdgcn_mfma_f32_16x16x32_bf16(pa0, vbl, acc_o[0][dt], 0, 0, 0);
        acc_o[1][dt] = __builtin_amdgcn_mfma_f32_16x16x32_bf16(pa1, vbh, acc_o[1][dt], 0, 0, 0);
        acc_o[1][dt] = __builtin_amdgcn_mfma_f32_16x16x32_bf16(pa1, vbl, acc_o[1][dt], 0, 0, 0);
      }
    }
    __syncthreads();
  }

  // normalize + store hi/lo into q-slice
  #pragma unroll
  for (int g = 0; g < 2; ++g)
    #pragma unroll
    for (int dt = 0; dt < 4; ++dt)
      #pragma unroll
      for (int r = 0; r < 4; ++r) {
        const int qrow = q0 + g * 16 + quad * 4 + r;
        const float inv = 1.0f / fmaxf(l_i[g][r], 1.0e-30f);
        const size_t off = (size_t)(b * kN + qrow) * k3C + h * kD + dt * 16 + l16;
        unsigned short hh, ll;
        split2(acc_o[g][dt][r] * inv, hh, ll);
        H[off] = hh; L[off] = ll;
      }
}

} // anonymous namespace

extern "C" void kernel_launch(void* const* d_in, const int* in_sizes, int n_in,
                              void* d_out, int out_size, void* d_ws, size_t ws_size,
                              hipStream_t stream)
{
  const float* x      = (const float*)d_in[0];
  const int*   maskp  = (const int*)d_in[1];
  const float* qkv_w  = (const float*)d_in[2];
  const float* qkv_b  = (const float*)d_in[3];
  const float* proj_w = (const float*)d_in[4];
  const float* proj_b = (const float*)d_in[5];
  const float* qn_w   = (const float*)d_in[6];
  const float* kn_w   = (const float*)d_in[7];
  float* out = (float*)d_out;

  unsigned short* qH = (unsigned short*)d_ws;      // qkv hi plane
  unsigned short* qL = qH + kPS;                   // qkv lo plane
  unsigned short* R1 = qL + kPS;                   // x planes -> later VT planes
  unsigned short* R2 = R1 + 2 * kXE;               // qkv_w planes -> later proj_w planes
  unsigned short* xH = R1,  *xL = R1 + kXE;
  unsigned short* VTH = R1, *VTL = R1 + kXE;
  unsigned short* wqH = R2, *wqL = R2 + kWQ;
  unsigned short* wpH = R2, *wpL = R2 + kWP;

  split_planes<<<(int)(kXE / 4 / 256), 256, 0, stream>>>(x, xH, xL, (int)(kXE / 4));
  split_planes<<<(int)(kWQ / 4 / 256), 256, 0, stream>>>(qkv_w, wqH, wqL, (int)(kWQ / 4));

  // 1) qkv = x @ qkv_w^T + qkv_b, RMSNorm(q,k) fused into epilogue
  gemm_planes<false, true><<<dim3(kTok / 128, k3C / 128), 256, 0, stream>>>(
      xH, xL, kC, wqH, wqL, qkv_b, nullptr, qH, qL, qn_w, kn_w, k3C, kC);

  // 2) pre-transpose V (overwrites x planes) ; pre-split proj_w (overwrites qkv_w)
  vt_transpose<<<2048, 256, 0, stream>>>(qH, qL, VTH, VTL);
  split_planes<<<(int)(kWP / 4 / 256), 256, 0, stream>>>(proj_w, wpH, wpL, (int)(kWP / 4));

  // 3) masked flash attention; result into q-slice of planes
  attn_kernel<<<dim3(kN / 128, kB * kH), 256, 0, stream>>>(qH, qL, VTH, VTL, maskp);

  // 4) out = attn @ proj_w^T + proj_b
  gemm_planes<true, false><<<dim3(kTok / 128, kC / 128), 256, 0, stream>>>(
      qH, qL, k3C, wpH, wpL, proj_b, out, nullptr, nullptr, nullptr, nullptr, kC, kC);
}